// Round 18
// baseline (560.032 us; speedup 1.0000x reference)
//
#include <hip/hip_runtime.h>
#include <hip/hip_bf16.h>
#include <math.h>

#define NN 50000
#define EE 800000
#define MM (EE + NN)   // edges + self loops
#define GG 64
#define SWG 512        // stat partial workgroups
#define NSB ((NN + 255) / 256)   // scan blocks = 196
#define PSP 16         // pooling splits per group

// adaptive int read: handles both int32 and int64 device buffers
__device__ __forceinline__ int geti(const void* p, long idx, int is64) {
    return is64 ? (int)((const long long*)p)[idx] : ((const int*)p)[idx];
}

__device__ __forceinline__ float bf2f(unsigned short u) {
    return __uint_as_float(((unsigned)u) << 16);
}

__device__ __forceinline__ float eluf(float z) {
    return z > 0.f ? z : expm1f(z);
}

// ---------------- CSR by destination ----------------

// zero + int64-detect fused (block 0 thread 0 does the detect)
__global__ void k_zero(int* p, int n, const int* __restrict__ ei, int* __restrict__ flag) {
    int i = blockIdx.x * blockDim.x + threadIdx.x;
    if (i < n) p[i] = 0;
    if (blockIdx.x == 0 && threadIdx.x == 0 && ei != nullptr) {
        int ok = 1;
        for (int k = 0; k < 128; ++k) {
            int lo = ei[2 * k], hi = ei[2 * k + 1];
            if (hi != 0 || (unsigned)lo >= (unsigned)NN) { ok = 0; break; }
        }
        flag[0] = ok;
    }
}

__global__ void k_count(const void* __restrict__ ei, const int* __restrict__ flag,
                        int* __restrict__ counts) {
    int e = blockIdx.x * blockDim.x + threadIdx.x;
    if (e >= MM) return;
    int is64 = flag[0];
    int d = (e < EE) ? geti(ei, (long)EE + e, is64) : (e - EE);
    if ((unsigned)d < (unsigned)NN) atomicAdd(&counts[d], 1);
}

// parallel scan: per-block inclusive scan + block sums
__global__ __launch_bounds__(256) void k_scan1(const int* __restrict__ counts,
                                               int* __restrict__ rowptr,
                                               int* __restrict__ bsum) {
    __shared__ int buf[256];
    int b = blockIdx.x, tid = threadIdx.x;
    int i = b * 256 + tid;
    int v = (i < NN) ? counts[i] : 0;
    buf[tid] = v;
    __syncthreads();
    for (int off = 1; off < 256; off <<= 1) {
        int t = (tid >= off) ? buf[tid - off] : 0;
        __syncthreads();
        buf[tid] += t;
        __syncthreads();
    }
    if (i < NN) rowptr[i + 1] = buf[tid];
    if (tid == 255) bsum[b] = buf[255];
}

__global__ __launch_bounds__(256) void k_scan2(int* __restrict__ bsum) {
    __shared__ int buf[256];
    int tid = threadIdx.x;
    int v = (tid < NSB) ? bsum[tid] : 0;
    buf[tid] = v;
    __syncthreads();
    for (int off = 1; off < 256; off <<= 1) {
        int t = (tid >= off) ? buf[tid - off] : 0;
        __syncthreads();
        buf[tid] += t;
        __syncthreads();
    }
    if (tid < NSB) bsum[tid] = (tid == 0) ? 0 : buf[tid - 1];
}

__global__ __launch_bounds__(256) void k_scan3(int* __restrict__ rowptr,
                                               const int* __restrict__ bsum) {
    int b = blockIdx.x, tid = threadIdx.x;
    int i = b * 256 + tid;
    if (i < NN) rowptr[i + 1] += bsum[b];
    if (b == 0 && tid == 0) rowptr[0] = 0;
}

__global__ void k_fill(const void* __restrict__ ei, const int* __restrict__ flag,
                       const int* __restrict__ rowptr,
                       int* __restrict__ fill, int* __restrict__ colv) {
    int e = blockIdx.x * blockDim.x + threadIdx.x;
    if (e >= MM) return;
    int is64 = flag[0];
    int s, d;
    if (e < EE) { s = geti(ei, e, is64); d = geti(ei, (long)EE + e, is64); }
    else { s = d = e - EE; }
    if ((unsigned)d >= (unsigned)NN || (unsigned)s >= (unsigned)NN) return;
    int pos = rowptr[d] + atomicAdd(&fill[d], 1);
    if ((unsigned)pos < (unsigned)MM) colv[pos] = s;
}

// ---------------- fused tiled GEMM + attention dots (bf16 xp out) ----------------
// tile: 128 rows x 64 cols, thread = 4 rows x 8 cols; Wt swizzled [kk][hh][12].

__global__ __launch_bounds__(256) void k_gemm_att(
    const float* __restrict__ hsrc, const float* __restrict__ Ysrc,
    const float* __restrict__ st, const float* __restrict__ W,
    const float* __restrict__ attS, const float* __restrict__ attD,
    unsigned short* __restrict__ xpb, float* __restrict__ als,
    float* __restrict__ ald, int n)
{
    __shared__ float Wt[32][8][12];
    __shared__ float Ht[128][33];
    int tid = threadIdx.x;
    int hh = tid & 7;
    int r0 = tid >> 3;
    int rbase = (blockIdx.x >> 1) * 128;
    int cbase = (blockIdx.x & 1) * 64;
    bool useY = (Ysrc != nullptr);

    float acc[4][8];
#pragma unroll
    for (int a = 0; a < 4; ++a)
#pragma unroll
        for (int b = 0; b < 8; ++b) acc[a][b] = 0.f;

    for (int k0 = 0; k0 < 128; k0 += 32) {
#pragma unroll
        for (int jj = 0; jj < 2; ++jj) {
            int idx = tid * 2 + jj;
            int kk = idx >> 4;
            int cpos = (idx & 15) * 4;
            int h2 = cpos >> 3, t = cpos & 7;
            *(float4*)&Wt[kk][h2][t] =
                *(const float4*)&W[(k0 + kk) * 128 + cbase + h2 * 8 + t];
        }
#pragma unroll
        for (int j = 0; j < 4; ++j) {
            int f = tid * 16 + j * 4;
            int r = f >> 5, kk = f & 31;
            int gr = rbase + r;
            float4 v = make_float4(0.f, 0.f, 0.f, 0.f);
            if (gr < n) {
                if (useY) {
                    float4 yv = *(const float4*)&Ysrc[gr * 128 + k0 + kk];
                    float4 scv = *(const float4*)&st[k0 + kk];
                    float4 shv = *(const float4*)&st[128 + k0 + kk];
                    v.x = eluf(fmaf(yv.x, scv.x, shv.x));
                    v.y = eluf(fmaf(yv.y, scv.y, shv.y));
                    v.z = eluf(fmaf(yv.z, scv.z, shv.z));
                    v.w = eluf(fmaf(yv.w, scv.w, shv.w));
                } else {
                    v = *(const float4*)&hsrc[gr * 128 + k0 + kk];
                }
            }
            Ht[r][kk] = v.x; Ht[r][kk + 1] = v.y; Ht[r][kk + 2] = v.z; Ht[r][kk + 3] = v.w;
        }
        __syncthreads();
#pragma unroll 4
        for (int kk = 0; kk < 32; ++kk) {
            float wv[8];
            *(float4*)&wv[0] = *(const float4*)&Wt[kk][hh][0];
            *(float4*)&wv[4] = *(const float4*)&Wt[kk][hh][4];
#pragma unroll
            for (int rr = 0; rr < 4; ++rr) {
                float hv = Ht[r0 + rr * 32][kk];
#pragma unroll
                for (int j = 0; j < 8; ++j) acc[rr][j] = fmaf(hv, wv[j], acc[rr][j]);
            }
        }
        __syncthreads();
    }

    int head = (cbase >> 4) + (hh >> 1);
    int halfsel = hh & 1;
    float asv[8], adv[8];
#pragma unroll
    for (int j = 0; j < 8; ++j) {
        asv[j] = attS[head * 16 + halfsel * 8 + j];
        adv[j] = attD[head * 16 + halfsel * 8 + j];
    }

#pragma unroll
    for (int rr = 0; rr < 4; ++rr) {
        int r = rbase + r0 + rr * 32;
        if (r < n) {
            float ds = 0.f, dd = 0.f;
#pragma unroll
            for (int j = 0; j < 8; ++j) { ds = fmaf(acc[rr][j], asv[j], ds); dd = fmaf(acc[rr][j], adv[j], dd); }
            ds += __shfl_xor(ds, 1);
            dd += __shfl_xor(dd, 1);
            if (halfsel == 0) {
                als[r * 8 + head] = ds;
                ald[r * 8 + head] = dd;
            }
            unsigned short xb[8];
#pragma unroll
            for (int j = 0; j < 8; ++j) {
                __hip_bfloat16 t = __float2bfloat16(acc[rr][j]);
                xb[j] = *reinterpret_cast<unsigned short*>(&t);
            }
            *(uint4*)&xpb[(size_t)r * 128 + cbase + hh * 8] = *(uint4*)&xb[0];
        }
    }
}

// ---------------- fused softmax + gather: TWO waves per node ----------------
// Each wave processes half the node's edge range (same batched-LDS gather),
// producing unnormalized partial accumulators + per-head partial denominators.
// Parity-1 wave publishes via LDS; parity-0 wave combines, normalizes, writes y.

__global__ __launch_bounds__(256) void k_agg(
    const unsigned short* __restrict__ xpb, const float* __restrict__ als,
    const float* __restrict__ ald,
    const int* __restrict__ rowptr, const int* __restrict__ colv,
    const float* __restrict__ prevRaw, const float* __restrict__ prevY,
    const float* __restrict__ pst, const float* __restrict__ bias,
    float* __restrict__ y, int n)
{
    __shared__ float alds[4][8][8];   // [wave][edge][head]
    __shared__ int   slds[4][8];      // [wave][edge]
    __shared__ float accs[2][128];    // [node-in-block][channel]
    __shared__ float dens[2][8];      // [node-in-block][head]
    int wv = threadIdx.x >> 6;               // wave in block 0..3
    long gw = (long)blockIdx.x * 4 + wv;     // global wave
    int wid = (int)(gw >> 1);
    int parity = (int)(gw & 1);
    int nb = wv >> 1;                        // node slot in block
    int lane = threadIdx.x & 63;
    bool live = (wid < n);
    int widc = live ? wid : (n - 1);

    int rs0 = rowptr[widc], re0 = rowptr[widc + 1];
    int degall = re0 - rs0;
    int h0 = degall >> 1;
    int rs  = (parity == 0) ? rs0 : rs0 + h0;
    int deg = (parity == 0) ? h0 : degall - h0;

    int hd = lane & 7;
    int ee = lane >> 3;
    float aldn = ald[widc * 8 + hd];
    int q = lane >> 3;
    int c0 = lane * 2;

    float a0 = 0.f, a1 = 0.f, smloc = 0.f;
    int full = deg & ~7;

    for (int b0 = 0; b0 < full; b0 += 8) {
        int se = colv[rs + b0 + ee];
        float v = als[se * 8 + hd] + aldn;
        v = v > 0.f ? v : 0.2f * v;
        float al = expf(v);
        smloc += al;
        alds[wv][ee][hd] = al;
        if (hd == 0) slds[wv][ee] = se;
#pragma unroll
        for (int j = 0; j < 8; ++j) {
            int s = slds[wv][j];
            float a = alds[wv][j][q];
            ushort2 xv = *(const ushort2*)(xpb + (size_t)s * 128 + c0);
            a0 = fmaf(a, bf2f(xv.x), a0);
            a1 = fmaf(a, bf2f(xv.y), a1);
        }
    }

    if (full < deg) {
        int nbt = deg - full;
        float al = 0.f;
        int se = 0;
        if (ee < nbt) {
            se = colv[rs + full + ee];
            float v = als[se * 8 + hd] + aldn;
            v = v > 0.f ? v : 0.2f * v;
            al = expf(v);
            smloc += al;
        }
        alds[wv][ee][hd] = al;
        if (hd == 0) slds[wv][ee] = se;
        for (int j = 0; j < nbt; ++j) {
            int s = slds[wv][j];
            float a = alds[wv][j][q];
            ushort2 xv = *(const ushort2*)(xpb + (size_t)s * 128 + c0);
            a0 = fmaf(a, bf2f(xv.x), a0);
            a1 = fmaf(a, bf2f(xv.y), a1);
        }
    }

    // butterfly: every lane gets its head's partial denominator
    smloc += __shfl_xor(smloc, 8);
    smloc += __shfl_xor(smloc, 16);
    smloc += __shfl_xor(smloc, 32);

    // publish parity-1 partials
    if (parity == 1) {
        accs[nb][c0] = a0;
        accs[nb][c0 + 1] = a1;
        if (lane < 8) dens[nb][lane] = smloc;   // lane's hd == lane for lane<8
    }
    __syncthreads();

    if (parity == 0 && live) {
        a0 += accs[nb][c0];
        a1 += accs[nb][c0 + 1];
        float dtot = __shfl(smloc, q) + dens[nb][q];
        float inv = 1.f / dtot;
        a0 *= inv;
        a1 *= inv;

        float p0 = 0.f, p1 = 0.f;
        if (prevY) {
            float2 yv = *(const float2*)(prevY + (size_t)widc * 128 + c0);
            p0 = eluf(fmaf(yv.x, pst[c0], pst[128 + c0]));
            p1 = eluf(fmaf(yv.y, pst[c0 + 1], pst[129 + c0]));
        } else if (prevRaw) {
            p0 = prevRaw[(size_t)widc * 128 + c0];
            p1 = prevRaw[(size_t)widc * 128 + c0 + 1];
        }
        y[widc * 128 + c0] = p0 + a0 + bias[c0];
        y[widc * 128 + c0 + 1] = p1 + a1 + bias[c0 + 1];
    }
}

// ---------------- layernorm over axis 0 ----------------

__global__ __launch_bounds__(256) void k_stats(const float* __restrict__ y,
                                               double* __restrict__ partial, int n) {
    int col = threadIdx.x & 127;
    int rg = threadIdx.x >> 7;
    double s = 0.0, s2 = 0.0;
    for (int r = blockIdx.x * 2 + rg; r < n; r += SWG * 2) {
        float v = y[r * 128 + col];
        s += v; s2 += (double)v * (double)v;
    }
    __shared__ double ls[256], ls2[256];
    ls[threadIdx.x] = s; ls2[threadIdx.x] = s2;
    __syncthreads();
    if (rg == 0) {
        s += ls[threadIdx.x + 128];
        s2 += ls2[threadIdx.x + 128];
        partial[col * SWG + blockIdx.x] = s;
        partial[128 * SWG + col * SWG + blockIdx.x] = s2;
    }
}

// finishes stats AND bakes gamma/beta into affine scale/shift:
// st[col] = gamma*rsig, st[128+col] = beta - mu*gamma*rsig
__global__ void k_stats_fin(const double* __restrict__ partial,
                            const float* __restrict__ gamma,
                            const float* __restrict__ beta,
                            float* __restrict__ st, int n) {
    int col = threadIdx.x;  // 128 threads
    double s = 0.0, s2 = 0.0;
    for (int w = 0; w < SWG; ++w) {
        s += partial[col * SWG + w];
        s2 += partial[128 * SWG + col * SWG + w];
    }
    double mu = s / n;
    double var = s2 / n - mu * mu;
    double rsig = 1.0 / sqrt(var + 1e-5);
    double sc = (double)gamma[col] * rsig;
    st[col] = (float)sc;
    st[128 + col] = (float)((double)beta[col] - mu * sc);
}

// ---------------- pooling: split stage + reduce/readout ----------------

__global__ __launch_bounds__(256) void k_pool_part(
    const float* __restrict__ Y, const float* __restrict__ st,
    const void* __restrict__ batch, const int* __restrict__ flag,
    float* __restrict__ ppart, int n)
{
    int g = blockIdx.x / PSP;
    int sp = blockIdx.x % PSP;
    int is64 = flag[0];
    int lo = 0, hi = n;
    while (lo < hi) { int mid = (lo + hi) >> 1; if (geti(batch, mid, is64) < g) lo = mid + 1; else hi = mid; }
    int start = lo;
    hi = n;
    while (lo < hi) { int mid = (lo + hi) >> 1; if (geti(batch, mid, is64) < g + 1) lo = mid + 1; else hi = mid; }
    int end = lo;
    int cnt = end - start;
    int slice = (cnt + PSP - 1) / PSP;
    int s0 = start + sp * slice;
    int s1 = s0 + slice; if (s1 > end) s1 = end;

    int col = threadIdx.x & 127;
    int half = threadIdx.x >> 7;
    float sc = st[col], sh = st[128 + col];
    float s = 0.f;
    for (int r = s0 + half; r < s1; r += 2)
        s += eluf(fmaf(Y[(size_t)r * 128 + col], sc, sh));
    __shared__ float ls[256];
    ls[threadIdx.x] = s;
    __syncthreads();
    if (half == 0) ppart[(g * PSP + sp) * 128 + col] = s + ls[col + 128];
}

__global__ __launch_bounds__(128) void k_pool_fin(
    const float* __restrict__ ppart, const void* __restrict__ batch,
    const int* __restrict__ flag, const float* __restrict__ row,
    const float* __restrict__ rob, float* __restrict__ out, int n)
{
    int g = blockIdx.x;
    int is64 = flag[0];
    int lo = 0, hi = n;
    while (lo < hi) { int mid = (lo + hi) >> 1; if (geti(batch, mid, is64) < g) lo = mid + 1; else hi = mid; }
    int start = lo;
    hi = n;
    while (lo < hi) { int mid = (lo + hi) >> 1; if (geti(batch, mid, is64) < g + 1) lo = mid + 1; else hi = mid; }
    int cnt = lo - start;

    int col = threadIdx.x;   // 128
    float s = 0.f;
#pragma unroll
    for (int sp = 0; sp < PSP; ++sp) s += ppart[(g * PSP + sp) * 128 + col];
    __shared__ float ls[128];
    ls[col] = s * (1.f / fmaxf((float)cnt, 1.f));
    __syncthreads();
    if (col < 2) {
        float acc = 0.f;
        for (int c = 0; c < 128; ++c) acc = fmaf(ls[c], row[c * 2 + col], acc);
        out[g * 2 + col] = acc + rob[col];
    }
}

// ---------------- launch ----------------

extern "C" void kernel_launch(void* const* d_in, const int* in_sizes, int n_in,
                              void* d_out, int out_size, void* d_ws, size_t ws_size,
                              hipStream_t stream) {
    const float* x     = (const float*)d_in[0];
    const void*  ei    = d_in[1];
    const void*  batch = d_in[2];
    const float* W     = (const float*)d_in[3];
    const float* attS  = (const float*)d_in[4];
    const float* attD  = (const float*)d_in[5];
    const float* bias  = (const float*)d_in[6];
    const float* gamma = (const float*)d_in[7];
    const float* beta  = (const float*)d_in[8];
    const float* row   = (const float*)d_in[9];
    const float* rob   = (const float*)d_in[10];
    float* out = (float*)d_out;

    char* wsb = (char*)d_ws;
    size_t off = 0;
    auto alloc = [&](size_t bytes) {
        void* p = wsb + off;
        off += (bytes + 255) & ~(size_t)255;
        return p;
    };
    int*    flag    = (int*)alloc(256);
    int*    rowptr  = (int*)alloc((size_t)(NN + 1) * 4);
    int*    cnts    = (int*)alloc((size_t)NN * 4 * 2);   // counts + fill
    int*    bsum    = (int*)alloc((size_t)256 * 4);
    int*    colv    = (int*)alloc((size_t)MM * 4);
    double* partial = (double*)alloc((size_t)128 * SWG * 2 * 8);
    float*  st1     = (float*)alloc(256 * 4);
    float*  st2     = (float*)alloc(256 * 4);
    float*  st3     = (float*)alloc(256 * 4);
    float*  ppart   = (float*)alloc((size_t)GG * PSP * 128 * 4);
    float*  ALS     = (float*)alloc((size_t)NN * 8 * 4);
    float*  ALD     = (float*)alloc((size_t)NN * 8 * 4);
    unsigned short* XPB = (unsigned short*)alloc((size_t)NN * 128 * 2);
    float* Y1 = (float*)alloc((size_t)NN * 128 * 4);
    float* Y2 = (float*)alloc((size_t)NN * 128 * 4);
    float* Y3 = (float*)alloc((size_t)NN * 128 * 4);
    (void)ws_size; (void)in_sizes; (void)n_in; (void)out_size;

    int* fill = cnts + NN;
    const int GB2 = ((NN + 127) / 128) * 2;   // gemm blocks
    const int GA2 = (2 * NN + 3) / 4;         // agg blocks (2 waves/node)

    hipLaunchKernelGGL(k_zero, dim3((2 * NN + 255) / 256), dim3(256), 0, stream,
                       cnts, 2 * NN, (const int*)ei, flag);
    hipLaunchKernelGGL(k_count, dim3((MM + 255) / 256), dim3(256), 0, stream, ei, flag, cnts);
    hipLaunchKernelGGL(k_scan1, dim3(NSB), dim3(256), 0, stream, cnts, rowptr, bsum);
    hipLaunchKernelGGL(k_scan2, dim3(1), dim3(256), 0, stream, bsum);
    hipLaunchKernelGGL(k_scan3, dim3(NSB), dim3(256), 0, stream, rowptr, bsum);
    hipLaunchKernelGGL(k_fill, dim3((MM + 255) / 256), dim3(256), 0, stream, ei, flag, rowptr, fill, colv);

    // ---- layer 0: h = x (raw), prev = 0 ----
    hipLaunchKernelGGL(k_gemm_att, dim3(GB2), dim3(256), 0, stream,
                       x, (const float*)nullptr, (const float*)nullptr,
                       W, attS, attD, XPB, ALS, ALD, NN);
    hipLaunchKernelGGL(k_agg, dim3(GA2), dim3(256), 0, stream,
                       XPB, ALS, ALD, rowptr, colv,
                       (const float*)nullptr, (const float*)nullptr, (const float*)nullptr,
                       bias, Y1, NN);
    hipLaunchKernelGGL(k_stats, dim3(SWG), dim3(256), 0, stream, Y1, partial, NN);
    hipLaunchKernelGGL(k_stats_fin, dim3(1), dim3(128), 0, stream, partial, gamma, beta, st1, NN);

    // ---- layer 1: h = E1(Y1), prev = x (raw) ----
    hipLaunchKernelGGL(k_gemm_att, dim3(GB2), dim3(256), 0, stream,
                       (const float*)nullptr, Y1, st1,
                       W + 16384, attS + 128, attD + 128, XPB, ALS, ALD, NN);
    hipLaunchKernelGGL(k_agg, dim3(GA2), dim3(256), 0, stream,
                       XPB, ALS, ALD, rowptr, colv,
                       x, (const float*)nullptr, (const float*)nullptr,
                       bias + 128, Y2, NN);
    hipLaunchKernelGGL(k_stats, dim3(SWG), dim3(256), 0, stream, Y2, partial, NN);
    hipLaunchKernelGGL(k_stats_fin, dim3(1), dim3(128), 0, stream, partial, gamma + 128, beta + 128, st2, NN);

    // ---- layer 2: h = E2(Y2), prev = E1(Y1) ----
    hipLaunchKernelGGL(k_gemm_att, dim3(GB2), dim3(256), 0, stream,
                       (const float*)nullptr, Y2, st2,
                       W + 32768, attS + 256, attD + 256, XPB, ALS, ALD, NN);
    hipLaunchKernelGGL(k_agg, dim3(GA2), dim3(256), 0, stream,
                       XPB, ALS, ALD, rowptr, colv,
                       (const float*)nullptr, Y1, st1,
                       bias + 256, Y3, NN);
    hipLaunchKernelGGL(k_stats, dim3(SWG), dim3(256), 0, stream, Y3, partial, NN);
    hipLaunchKernelGGL(k_stats_fin, dim3(1), dim3(128), 0, stream, partial, gamma + 256, beta + 256, st3, NN);

    // ---- pooling on E3(Y3) ----
    hipLaunchKernelGGL(k_pool_part, dim3(GG * PSP), dim3(256), 0, stream,
                       Y3, st3, batch, flag, ppart, NN);
    hipLaunchKernelGGL(k_pool_fin, dim3(GG), dim3(128), 0, stream,
                       ppart, batch, flag, row, rob, out, NN);
}

// Round 19
// 543.028 us; speedup vs baseline: 1.0313x; 1.0313x over previous
//
#include <hip/hip_runtime.h>
#include <hip/hip_bf16.h>
#include <math.h>

#define NN 50000
#define EE 800000
#define MM (EE + NN)   // edges + self loops
#define GG 64
#define SWG 512        // stat partial workgroups
#define NSB ((NN + 255) / 256)   // scan blocks = 196
#define PSP 16         // pooling splits per group

// adaptive int read: handles both int32 and int64 device buffers
__device__ __forceinline__ int geti(const void* p, long idx, int is64) {
    return is64 ? (int)((const long long*)p)[idx] : ((const int*)p)[idx];
}

__device__ __forceinline__ float bf2f(unsigned short u) {
    return __uint_as_float(((unsigned)u) << 16);
}

__device__ __forceinline__ float eluf(float z) {
    return z > 0.f ? z : expm1f(z);
}

// ---------------- CSR by destination ----------------

// zero + int64-detect fused (block 0 thread 0 does the detect)
__global__ void k_zero(int* p, int n, const int* __restrict__ ei, int* __restrict__ flag) {
    int i = blockIdx.x * blockDim.x + threadIdx.x;
    if (i < n) p[i] = 0;
    if (blockIdx.x == 0 && threadIdx.x == 0 && ei != nullptr) {
        int ok = 1;
        for (int k = 0; k < 128; ++k) {
            int lo = ei[2 * k], hi = ei[2 * k + 1];
            if (hi != 0 || (unsigned)lo >= (unsigned)NN) { ok = 0; break; }
        }
        flag[0] = ok;
    }
}

__global__ void k_count(const void* __restrict__ ei, const int* __restrict__ flag,
                        int* __restrict__ counts) {
    int e = blockIdx.x * blockDim.x + threadIdx.x;
    if (e >= MM) return;
    int is64 = flag[0];
    int d = (e < EE) ? geti(ei, (long)EE + e, is64) : (e - EE);
    if ((unsigned)d < (unsigned)NN) atomicAdd(&counts[d], 1);
}

// parallel scan: per-block inclusive scan + block sums
__global__ __launch_bounds__(256) void k_scan1(const int* __restrict__ counts,
                                               int* __restrict__ rowptr,
                                               int* __restrict__ bsum) {
    __shared__ int buf[256];
    int b = blockIdx.x, tid = threadIdx.x;
    int i = b * 256 + tid;
    int v = (i < NN) ? counts[i] : 0;
    buf[tid] = v;
    __syncthreads();
    for (int off = 1; off < 256; off <<= 1) {
        int t = (tid >= off) ? buf[tid - off] : 0;
        __syncthreads();
        buf[tid] += t;
        __syncthreads();
    }
    if (i < NN) rowptr[i + 1] = buf[tid];
    if (tid == 255) bsum[b] = buf[255];
}

__global__ __launch_bounds__(256) void k_scan2(int* __restrict__ bsum) {
    __shared__ int buf[256];
    int tid = threadIdx.x;
    int v = (tid < NSB) ? bsum[tid] : 0;
    buf[tid] = v;
    __syncthreads();
    for (int off = 1; off < 256; off <<= 1) {
        int t = (tid >= off) ? buf[tid - off] : 0;
        __syncthreads();
        buf[tid] += t;
        __syncthreads();
    }
    if (tid < NSB) bsum[tid] = (tid == 0) ? 0 : buf[tid - 1];
}

__global__ __launch_bounds__(256) void k_scan3(int* __restrict__ rowptr,
                                               const int* __restrict__ bsum) {
    int b = blockIdx.x, tid = threadIdx.x;
    int i = b * 256 + tid;
    if (i < NN) rowptr[i + 1] += bsum[b];
    if (b == 0 && tid == 0) rowptr[0] = 0;
}

__global__ void k_fill(const void* __restrict__ ei, const int* __restrict__ flag,
                       const int* __restrict__ rowptr,
                       int* __restrict__ fill, int* __restrict__ colv) {
    int e = blockIdx.x * blockDim.x + threadIdx.x;
    if (e >= MM) return;
    int is64 = flag[0];
    int s, d;
    if (e < EE) { s = geti(ei, e, is64); d = geti(ei, (long)EE + e, is64); }
    else { s = d = e - EE; }
    if ((unsigned)d >= (unsigned)NN || (unsigned)s >= (unsigned)NN) return;
    int pos = rowptr[d] + atomicAdd(&fill[d], 1);
    if ((unsigned)pos < (unsigned)MM) colv[pos] = s;
}

// ---------------- fused tiled GEMM + attention dots (bf16 xp out) ----------------
// tile: 128 rows x 64 cols, thread = 4 rows x 8 cols; Wt swizzled [kk][hh][12].

__global__ __launch_bounds__(256) void k_gemm_att(
    const float* __restrict__ hsrc, const float* __restrict__ Ysrc,
    const float* __restrict__ st, const float* __restrict__ W,
    const float* __restrict__ attS, const float* __restrict__ attD,
    unsigned short* __restrict__ xpb, float* __restrict__ als,
    float* __restrict__ ald, int n)
{
    __shared__ float Wt[32][8][12];
    __shared__ float Ht[128][33];
    int tid = threadIdx.x;
    int hh = tid & 7;
    int r0 = tid >> 3;
    int rbase = (blockIdx.x >> 1) * 128;
    int cbase = (blockIdx.x & 1) * 64;
    bool useY = (Ysrc != nullptr);

    float acc[4][8];
#pragma unroll
    for (int a = 0; a < 4; ++a)
#pragma unroll
        for (int b = 0; b < 8; ++b) acc[a][b] = 0.f;

    for (int k0 = 0; k0 < 128; k0 += 32) {
#pragma unroll
        for (int jj = 0; jj < 2; ++jj) {
            int idx = tid * 2 + jj;
            int kk = idx >> 4;
            int cpos = (idx & 15) * 4;
            int h2 = cpos >> 3, t = cpos & 7;
            *(float4*)&Wt[kk][h2][t] =
                *(const float4*)&W[(k0 + kk) * 128 + cbase + h2 * 8 + t];
        }
#pragma unroll
        for (int j = 0; j < 4; ++j) {
            int f = tid * 16 + j * 4;
            int r = f >> 5, kk = f & 31;
            int gr = rbase + r;
            float4 v = make_float4(0.f, 0.f, 0.f, 0.f);
            if (gr < n) {
                if (useY) {
                    float4 yv = *(const float4*)&Ysrc[gr * 128 + k0 + kk];
                    float4 scv = *(const float4*)&st[k0 + kk];
                    float4 shv = *(const float4*)&st[128 + k0 + kk];
                    v.x = eluf(fmaf(yv.x, scv.x, shv.x));
                    v.y = eluf(fmaf(yv.y, scv.y, shv.y));
                    v.z = eluf(fmaf(yv.z, scv.z, shv.z));
                    v.w = eluf(fmaf(yv.w, scv.w, shv.w));
                } else {
                    v = *(const float4*)&hsrc[gr * 128 + k0 + kk];
                }
            }
            Ht[r][kk] = v.x; Ht[r][kk + 1] = v.y; Ht[r][kk + 2] = v.z; Ht[r][kk + 3] = v.w;
        }
        __syncthreads();
#pragma unroll 4
        for (int kk = 0; kk < 32; ++kk) {
            float wv[8];
            *(float4*)&wv[0] = *(const float4*)&Wt[kk][hh][0];
            *(float4*)&wv[4] = *(const float4*)&Wt[kk][hh][4];
#pragma unroll
            for (int rr = 0; rr < 4; ++rr) {
                float hv = Ht[r0 + rr * 32][kk];
#pragma unroll
                for (int j = 0; j < 8; ++j) acc[rr][j] = fmaf(hv, wv[j], acc[rr][j]);
            }
        }
        __syncthreads();
    }

    int head = (cbase >> 4) + (hh >> 1);
    int halfsel = hh & 1;
    float asv[8], adv[8];
#pragma unroll
    for (int j = 0; j < 8; ++j) {
        asv[j] = attS[head * 16 + halfsel * 8 + j];
        adv[j] = attD[head * 16 + halfsel * 8 + j];
    }

#pragma unroll
    for (int rr = 0; rr < 4; ++rr) {
        int r = rbase + r0 + rr * 32;
        if (r < n) {
            float ds = 0.f, dd = 0.f;
#pragma unroll
            for (int j = 0; j < 8; ++j) { ds = fmaf(acc[rr][j], asv[j], ds); dd = fmaf(acc[rr][j], adv[j], dd); }
            ds += __shfl_xor(ds, 1);
            dd += __shfl_xor(dd, 1);
            if (halfsel == 0) {
                als[r * 8 + head] = ds;
                ald[r * 8 + head] = dd;
            }
            unsigned short xb[8];
#pragma unroll
            for (int j = 0; j < 8; ++j) {
                __hip_bfloat16 t = __float2bfloat16(acc[rr][j]);
                xb[j] = *reinterpret_cast<unsigned short*>(&t);
            }
            *(uint4*)&xpb[(size_t)r * 128 + cbase + hh * 8] = *(uint4*)&xb[0];
        }
    }
}

// ---------------- fused wave-per-node softmax + gather (shfl-based, no LDS) ----------------
// Single pass, unnormalized accumulation. Per batch of 8 edges, all 64 lanes
// compute exp(v) for (edge ee, head hd); gather phase pulls alpha/src via
// __shfl (lane j*8+q holds alpha[edge j][head q], lane j*8 holds src[j]).

__global__ __launch_bounds__(256) void k_agg(
    const unsigned short* __restrict__ xpb, const float* __restrict__ als,
    const float* __restrict__ ald,
    const int* __restrict__ rowptr, const int* __restrict__ colv,
    const float* __restrict__ prevRaw, const float* __restrict__ prevY,
    const float* __restrict__ pst, const float* __restrict__ bias,
    float* __restrict__ y, int n)
{
    int wid = (int)((blockIdx.x * blockDim.x + threadIdx.x) >> 6);
    int lane = threadIdx.x & 63;
    if (wid >= n) return;
    int rs = rowptr[wid], re = rowptr[wid + 1];
    int deg = re - rs;

    int hd = lane & 7;
    int ee = lane >> 3;
    float aldn = ald[wid * 8 + hd];
    int q = ee;              // head index for gather phase
    int c0 = lane * 2;

    float a0 = 0.f, a1 = 0.f, smloc = 0.f;
    int full = deg & ~7;

    for (int b0 = 0; b0 < full; b0 += 8) {
        int se = colv[rs + b0 + ee];
        float v = als[se * 8 + hd] + aldn;
        v = v > 0.f ? v : 0.2f * v;
        float al = expf(v);
        smloc += al;
#pragma unroll
        for (int j = 0; j < 8; ++j) {
            float a = __shfl(al, j * 8 + q);
            int s = __shfl(se, j * 8);
            ushort2 xv = *(const ushort2*)(xpb + (size_t)s * 128 + c0);
            a0 = fmaf(a, bf2f(xv.x), a0);
            a1 = fmaf(a, bf2f(xv.y), a1);
        }
    }

    if (full < deg) {
        int nb = deg - full;
        float al = 0.f;
        int se = 0;
        if (ee < nb) {
            se = colv[rs + full + ee];
            float v = als[se * 8 + hd] + aldn;
            v = v > 0.f ? v : 0.2f * v;
            al = expf(v);
            smloc += al;
        }
        for (int j = 0; j < nb; ++j) {
            float a = __shfl(al, j * 8 + q);
            int s = __shfl(se, j * 8);
            ushort2 xv = *(const ushort2*)(xpb + (size_t)s * 128 + c0);
            a0 = fmaf(a, bf2f(xv.x), a0);
            a1 = fmaf(a, bf2f(xv.y), a1);
        }
    }

    // reduce denominators across edge-slots (same head), fetch head q's total
    smloc += __shfl_xor(smloc, 8);
    smloc += __shfl_xor(smloc, 16);
    smloc += __shfl_xor(smloc, 32);
    float inv = 1.f / __shfl(smloc, q);   // lane q (q<8) has hd==q
    a0 *= inv;
    a1 *= inv;

    float p0 = 0.f, p1 = 0.f;
    if (prevY) {
        float2 yv = *(const float2*)(prevY + (size_t)wid * 128 + c0);
        p0 = eluf(fmaf(yv.x, pst[c0], pst[128 + c0]));
        p1 = eluf(fmaf(yv.y, pst[c0 + 1], pst[129 + c0]));
    } else if (prevRaw) {
        p0 = prevRaw[(size_t)wid * 128 + c0];
        p1 = prevRaw[(size_t)wid * 128 + c0 + 1];
    }
    y[wid * 128 + c0] = p0 + a0 + bias[c0];
    y[wid * 128 + c0 + 1] = p1 + a1 + bias[c0 + 1];
}

// ---------------- layernorm over axis 0 ----------------

__global__ __launch_bounds__(256) void k_stats(const float* __restrict__ y,
                                               double* __restrict__ partial, int n) {
    int col = threadIdx.x & 127;
    int rg = threadIdx.x >> 7;
    double s = 0.0, s2 = 0.0;
    for (int r = blockIdx.x * 2 + rg; r < n; r += SWG * 2) {
        float v = y[r * 128 + col];
        s += v; s2 += (double)v * (double)v;
    }
    __shared__ double ls[256], ls2[256];
    ls[threadIdx.x] = s; ls2[threadIdx.x] = s2;
    __syncthreads();
    if (rg == 0) {
        s += ls[threadIdx.x + 128];
        s2 += ls2[threadIdx.x + 128];
        partial[col * SWG + blockIdx.x] = s;
        partial[128 * SWG + col * SWG + blockIdx.x] = s2;
    }
}

// finishes stats AND bakes gamma/beta into affine scale/shift:
// st[col] = gamma*rsig, st[128+col] = beta - mu*gamma*rsig
__global__ void k_stats_fin(const double* __restrict__ partial,
                            const float* __restrict__ gamma,
                            const float* __restrict__ beta,
                            float* __restrict__ st, int n) {
    int col = threadIdx.x;  // 128 threads
    double s = 0.0, s2 = 0.0;
    for (int w = 0; w < SWG; ++w) {
        s += partial[col * SWG + w];
        s2 += partial[128 * SWG + col * SWG + w];
    }
    double mu = s / n;
    double var = s2 / n - mu * mu;
    double rsig = 1.0 / sqrt(var + 1e-5);
    double sc = (double)gamma[col] * rsig;
    st[col] = (float)sc;
    st[128 + col] = (float)((double)beta[col] - mu * sc);
}

// ---------------- pooling: split stage + reduce/readout ----------------

__global__ __launch_bounds__(256) void k_pool_part(
    const float* __restrict__ Y, const float* __restrict__ st,
    const void* __restrict__ batch, const int* __restrict__ flag,
    float* __restrict__ ppart, int n)
{
    int g = blockIdx.x / PSP;
    int sp = blockIdx.x % PSP;
    int is64 = flag[0];
    int lo = 0, hi = n;
    while (lo < hi) { int mid = (lo + hi) >> 1; if (geti(batch, mid, is64) < g) lo = mid + 1; else hi = mid; }
    int start = lo;
    hi = n;
    while (lo < hi) { int mid = (lo + hi) >> 1; if (geti(batch, mid, is64) < g + 1) lo = mid + 1; else hi = mid; }
    int end = lo;
    int cnt = end - start;
    int slice = (cnt + PSP - 1) / PSP;
    int s0 = start + sp * slice;
    int s1 = s0 + slice; if (s1 > end) s1 = end;

    int col = threadIdx.x & 127;
    int half = threadIdx.x >> 7;
    float sc = st[col], sh = st[128 + col];
    float s = 0.f;
    for (int r = s0 + half; r < s1; r += 2)
        s += eluf(fmaf(Y[(size_t)r * 128 + col], sc, sh));
    __shared__ float ls[256];
    ls[threadIdx.x] = s;
    __syncthreads();
    if (half == 0) ppart[(g * PSP + sp) * 128 + col] = s + ls[col + 128];
}

__global__ __launch_bounds__(128) void k_pool_fin(
    const float* __restrict__ ppart, const void* __restrict__ batch,
    const int* __restrict__ flag, const float* __restrict__ row,
    const float* __restrict__ rob, float* __restrict__ out, int n)
{
    int g = blockIdx.x;
    int is64 = flag[0];
    int lo = 0, hi = n;
    while (lo < hi) { int mid = (lo + hi) >> 1; if (geti(batch, mid, is64) < g) lo = mid + 1; else hi = mid; }
    int start = lo;
    hi = n;
    while (lo < hi) { int mid = (lo + hi) >> 1; if (geti(batch, mid, is64) < g + 1) lo = mid + 1; else hi = mid; }
    int cnt = lo - start;

    int col = threadIdx.x;   // 128
    float s = 0.f;
#pragma unroll
    for (int sp = 0; sp < PSP; ++sp) s += ppart[(g * PSP + sp) * 128 + col];
    __shared__ float ls[128];
    ls[col] = s * (1.f / fmaxf((float)cnt, 1.f));
    __syncthreads();
    if (col < 2) {
        float acc = 0.f;
        for (int c = 0; c < 128; ++c) acc = fmaf(ls[c], row[c * 2 + col], acc);
        out[g * 2 + col] = acc + rob[col];
    }
}

// ---------------- launch ----------------

extern "C" void kernel_launch(void* const* d_in, const int* in_sizes, int n_in,
                              void* d_out, int out_size, void* d_ws, size_t ws_size,
                              hipStream_t stream) {
    const float* x     = (const float*)d_in[0];
    const void*  ei    = d_in[1];
    const void*  batch = d_in[2];
    const float* W     = (const float*)d_in[3];
    const float* attS  = (const float*)d_in[4];
    const float* attD  = (const float*)d_in[5];
    const float* bias  = (const float*)d_in[6];
    const float* gamma = (const float*)d_in[7];
    const float* beta  = (const float*)d_in[8];
    const float* row   = (const float*)d_in[9];
    const float* rob   = (const float*)d_in[10];
    float* out = (float*)d_out;

    char* wsb = (char*)d_ws;
    size_t off = 0;
    auto alloc = [&](size_t bytes) {
        void* p = wsb + off;
        off += (bytes + 255) & ~(size_t)255;
        return p;
    };
    int*    flag    = (int*)alloc(256);
    int*    rowptr  = (int*)alloc((size_t)(NN + 1) * 4);
    int*    cnts    = (int*)alloc((size_t)NN * 4 * 2);   // counts + fill
    int*    bsum    = (int*)alloc((size_t)256 * 4);
    int*    colv    = (int*)alloc((size_t)MM * 4);
    double* partial = (double*)alloc((size_t)128 * SWG * 2 * 8);
    float*  st1     = (float*)alloc(256 * 4);
    float*  st2     = (float*)alloc(256 * 4);
    float*  st3     = (float*)alloc(256 * 4);
    float*  ppart   = (float*)alloc((size_t)GG * PSP * 128 * 4);
    float*  ALS     = (float*)alloc((size_t)NN * 8 * 4);
    float*  ALD     = (float*)alloc((size_t)NN * 8 * 4);
    unsigned short* XPB = (unsigned short*)alloc((size_t)NN * 128 * 2);
    float* Y1 = (float*)alloc((size_t)NN * 128 * 4);
    float* Y2 = (float*)alloc((size_t)NN * 128 * 4);
    float* Y3 = (float*)alloc((size_t)NN * 128 * 4);
    (void)ws_size; (void)in_sizes; (void)n_in; (void)out_size;

    int* fill = cnts + NN;
    const int GB2 = ((NN + 127) / 128) * 2;   // gemm blocks
    const int GA = (NN + 3) / 4;              // agg blocks (wave per node)

    hipLaunchKernelGGL(k_zero, dim3((2 * NN + 255) / 256), dim3(256), 0, stream,
                       cnts, 2 * NN, (const int*)ei, flag);
    hipLaunchKernelGGL(k_count, dim3((MM + 255) / 256), dim3(256), 0, stream, ei, flag, cnts);
    hipLaunchKernelGGL(k_scan1, dim3(NSB), dim3(256), 0, stream, cnts, rowptr, bsum);
    hipLaunchKernelGGL(k_scan2, dim3(1), dim3(256), 0, stream, bsum);
    hipLaunchKernelGGL(k_scan3, dim3(NSB), dim3(256), 0, stream, rowptr, bsum);
    hipLaunchKernelGGL(k_fill, dim3((MM + 255) / 256), dim3(256), 0, stream, ei, flag, rowptr, fill, colv);

    // ---- layer 0: h = x (raw), prev = 0 ----
    hipLaunchKernelGGL(k_gemm_att, dim3(GB2), dim3(256), 0, stream,
                       x, (const float*)nullptr, (const float*)nullptr,
                       W, attS, attD, XPB, ALS, ALD, NN);
    hipLaunchKernelGGL(k_agg, dim3(GA), dim3(256), 0, stream,
                       XPB, ALS, ALD, rowptr, colv,
                       (const float*)nullptr, (const float*)nullptr, (const float*)nullptr,
                       bias, Y1, NN);
    hipLaunchKernelGGL(k_stats, dim3(SWG), dim3(256), 0, stream, Y1, partial, NN);
    hipLaunchKernelGGL(k_stats_fin, dim3(1), dim3(128), 0, stream, partial, gamma, beta, st1, NN);

    // ---- layer 1: h = E1(Y1), prev = x (raw) ----
    hipLaunchKernelGGL(k_gemm_att, dim3(GB2), dim3(256), 0, stream,
                       (const float*)nullptr, Y1, st1,
                       W + 16384, attS + 128, attD + 128, XPB, ALS, ALD, NN);
    hipLaunchKernelGGL(k_agg, dim3(GA), dim3(256), 0, stream,
                       XPB, ALS, ALD, rowptr, colv,
                       x, (const float*)nullptr, (const float*)nullptr,
                       bias + 128, Y2, NN);
    hipLaunchKernelGGL(k_stats, dim3(SWG), dim3(256), 0, stream, Y2, partial, NN);
    hipLaunchKernelGGL(k_stats_fin, dim3(1), dim3(128), 0, stream, partial, gamma + 128, beta + 128, st2, NN);

    // ---- layer 2: h = E2(Y2), prev = E1(Y1) ----
    hipLaunchKernelGGL(k_gemm_att, dim3(GB2), dim3(256), 0, stream,
                       (const float*)nullptr, Y2, st2,
                       W + 32768, attS + 256, attD + 256, XPB, ALS, ALD, NN);
    hipLaunchKernelGGL(k_agg, dim3(GA), dim3(256), 0, stream,
                       XPB, ALS, ALD, rowptr, colv,
                       (const float*)nullptr, Y1, st1,
                       bias + 256, Y3, NN);
    hipLaunchKernelGGL(k_stats, dim3(SWG), dim3(256), 0, stream, Y3, partial, NN);
    hipLaunchKernelGGL(k_stats_fin, dim3(1), dim3(128), 0, stream, partial, gamma + 256, beta + 256, st3, NN);

    // ---- pooling on E3(Y3) ----
    hipLaunchKernelGGL(k_pool_part, dim3(GG * PSP), dim3(256), 0, stream,
                       Y3, st3, batch, flag, ppart, NN);
    hipLaunchKernelGGL(k_pool_fin, dim3(GG), dim3(128), 0, stream,
                       ppart, batch, flag, row, rob, out, NN);
}